// Round 7
// baseline (350.233 us; speedup 1.0000x reference)
//
#include <hip/hip_runtime.h>
#include <cstddef>

typedef float f2 __attribute__((ext_vector_type(2)));
typedef float f4 __attribute__((ext_vector_type(4)));
typedef _Float16 h2 __attribute__((ext_vector_type(2)));
typedef _Float16 h8 __attribute__((ext_vector_type(8)));

#define THRESH_V 10.0f
#define WPB 2            // waves per block (128 threads); each wave = 2 rows
#define SLICE_F2 928     // f2 units per wave slice (7424 B; 11 blocks/CU = 22 waves)

// ---- LDS geometry (f2-unit indices within a wave's slice) ----
// X region: ca2 base 6 (ext units 0..145), d2 @146 (..278), ca3 base 286
//   (ext 280..362), d3 @364 (..433), ca4 @434 (..471), d4 @472 (..509)
//   rec133 overlays [0,134) (ca2 dead; d2 still live)
// Y region: ca1 base 516 (ext units 510..781); rec70 @510 (..579) after ca1
//   dies; rec259 @510 (..768) after rec70 dies. d1 never overlapped.
// Z region: d1 = h2[260] at unit 784 (..913); unit U = D1B + (i>>1)
#define CA2B 6
#define D2B  146
#define CA3B 286
#define D3B  364
#define CA4B 434
#define D4B  472
#define REC133B 0
#define REC70B  510
#define REC259B 510
#define CA1B 516
#define D1B  784

// Waves are fully independent (one row-pair each, private LDS slice) -> no
// block barriers. lgkmcnt(0) drains this wave's DS queue so cross-lane LDS
// values are visible; "memory" clobber stops cross-stage code motion.
static __device__ __forceinline__ void wave_sync() {
  asm volatile("s_waitcnt lgkmcnt(0)" ::: "memory");
}

// XOR bank swizzle: permutes f2 units within each aligned 128B (16-unit)
// block. Bijective (overlay-safe), keeps bit0 (f4 pairing + 16B alignment
// preserved). Spreads blocked-window accesses (granule strides 2/3/4) to
// <=2-way bank aliasing instead of 16-way.
static __device__ __forceinline__ int swz(int U) {
  return U ^ (((U >> 4) & 7) << 1);
}

// ---- decomposition filters ----
#define L0f (-0.07576571478927333f)
#define L1f (-0.02963552764599851f)
#define L2f ( 0.49761866763201545f)
#define L3f ( 0.8037387518059161f)
#define L4f ( 0.29785779560527736f)
#define L5f (-0.09921954357684722f)
#define L6f (-0.012603967262037833f)
#define L7f ( 0.0322231006040427f)
#define H0f (-0.0322231006040427f)
#define H1f (-0.012603967262037833f)
#define H2f ( 0.09921954357684722f)
#define H3f ( 0.29785779560527736f)
#define H4f (-0.8037387518059161f)
#define H5f ( 0.49761866763201545f)
#define H6f ( 0.02963552764599851f)
#define H7f (-0.07576571478927333f)

static __device__ __forceinline__ f2 lo2(f4 w) { return __builtin_shufflevector(w, w, 0, 1); }
static __device__ __forceinline__ f2 hi2(f4 w) { return __builtin_shufflevector(w, w, 2, 3); }
static __device__ __forceinline__ float thr(float x) {
  return (fabsf(x) <= THRESH_V) ? x : 0.f;
}

// Exact accumulation model per row (element-wise across the f2 row pair):
//   p_t = fl(v_t * w_t)   (rounded products, NO fma)
//   y   = ((p0+p1)+(p2+p3)) + ((p4+p5)+(p6+p7))   (fixed pairwise tree)
// RLO[t]=L(7-t), RHI[t]=H(7-t). fp contract OFF: cA feeds later thresholds.
static __device__ __forceinline__ void fwd_core(f2 v0, f2 v1, f2 v2, f2 v3,
                                                f2 v4, f2 v5, f2 v6, f2 v7,
                                                f2& sLo, f2& sHi) {
#pragma clang fp contract(off)
  sLo = ((v0 * L7f + v1 * L6f) + (v2 * L5f + v3 * L4f)) +
        ((v4 * L3f + v5 * L2f) + (v6 * L1f + v7 * L0f));
  sHi = ((v0 * H7f + v1 * H6f) + (v2 * H5f + v3 * H4f)) +
        ((v4 * H3f + v5 * H2f) + (v6 * H1f + v7 * H0f));
}

// Forward DWT stage on LDS input (interleaved row-pair units, margins
// pre-filled by producer). BLOCKED: lane l computes outputs i0=B*l..i0+B-1
// from one shared window of B+3 16B granules (swizzled f4 reads).
// MARGINS: this stage writes its own ca mirrors (ext[-1-i]=ca[i] for i<6,
// ext[2M-1-i]=ca[i] for i>=M-7) -> no separate fill pass, no extra sync.
template <int N, int B, bool MARGINS>
static __device__ __forceinline__ void fwd_lds(f2* __restrict__ Sp, int INB,
                                               int CAB, int DB, int lane) {
  constexpr int M = (N + 7) >> 1;
  const int i0 = B * lane;
  if (i0 < M) {
    f2 w[2 * (B + 3)];
    const int u0 = INB + 2 * i0 - 6;   // even unit
#pragma unroll
    for (int k = 0; k < B + 3; ++k) {
      const f4 t = *(const f4*)(Sp + swz(u0 + 2 * k));
      w[2 * k] = lo2(t);
      w[2 * k + 1] = hi2(t);
    }
    f2 sA[B], sD[B];
#pragma unroll
    for (int j = 0; j < B; ++j) {
      f2 lo, hi;
      fwd_core(w[2*j+0], w[2*j+1], w[2*j+2], w[2*j+3],
               w[2*j+4], w[2*j+5], w[2*j+6], w[2*j+7], lo, hi);
      sA[j] = lo;
      f2 d; d.x = thr(hi.x); d.y = thr(hi.y);
      sD[j] = d;
      if constexpr (MARGINS) {
        const int i = i0 + j;
        if (i < 6 && i < M)        Sp[swz(CAB - 1 - i)]         = lo;
        if (i >= M - 7 && i < M)   Sp[swz(CAB + 2 * M - 1 - i)] = lo;
      }
    }
    if constexpr (B == 2) {   // M even at this level -> all blocks full
      f4 c; c.x = sA[0].x; c.y = sA[0].y; c.z = sA[1].x; c.w = sA[1].y;
      *(f4*)(Sp + swz(CAB + i0)) = c;
      f4 d; d.x = sD[0].x; d.y = sD[0].y; d.z = sD[1].x; d.w = sD[1].y;
      *(f4*)(Sp + swz(DB + i0)) = d;
    } else {                  // B==3 / B==1: scalar guarded stores
#pragma unroll
      for (int j = 0; j < B; ++j) {
        const int i = i0 + j;
        if (i < M) {
          Sp[swz(CAB + i)] = sA[j];
          Sp[swz(DB + i)]  = sD[j];
        }
      }
    }
  }
}

// Inverse DWT stage, BLOCKED: lane l handles pairs t0=B*l..t0+B-1 (outputs
// q=2t,2t+1) from one shared ca/cd window [t0, t0+B+2]. fma allowed (no
// threshold decisions downstream; 0.81 tolerance dwarfs rounding).
//   even q: taps L1,L3,L5,L7 / H1,H3,H5,H7;  odd q: L0,L2,L4,L6 / H0..H6
template <int OUT, int B, bool D16, bool GOUT>
static __device__ __forceinline__ void inv_lds(f2* __restrict__ Sp, int CAB,
                                               int DB, int DSTB,
                                               float* __restrict__ gA,
                                               float* __restrict__ gB,
                                               bool hasB, int lane) {
#pragma clang fp contract(fast)
  constexpr int P = (OUT + 1) >> 1;
  const int t0 = B * lane;
  if (t0 < P) {
    f2 a[B + 3], e[B + 3];
    if constexpr (B == 1) {   // odd lane starts -> scalar b64 reads
#pragma unroll
      for (int k = 0; k < 4; ++k) {
        a[k] = Sp[swz(CAB + t0 + k)];
        e[k] = Sp[swz(DB + t0 + k)];
      }
    } else {
      constexpr int NR = (B + 4) / 2;
#pragma unroll
      for (int k = 0; k < NR; ++k) {
        const f4 t = *(const f4*)(Sp + swz(CAB + t0 + 2 * k));
        if (2 * k     < B + 3) a[2 * k]     = lo2(t);
        if (2 * k + 1 < B + 3) a[2 * k + 1] = hi2(t);
      }
      if constexpr (D16) {    // d1: h2 array; t0=4l -> unit D1B+2l, 2x f4
        const f4 r0 = *(const f4*)(Sp + swz(DB + (t0 >> 1)));
        const f4 r1 = *(const f4*)(Sp + swz(DB + (t0 >> 1) + 2));
        const float rr[8] = {r0.x, r0.y, r0.z, r0.w, r1.x, r1.y, r1.z, r1.w};
#pragma unroll
        for (int k = 0; k < B + 3; ++k) {
          const h2 hx = __builtin_bit_cast(h2, rr[k]);
          e[k].x = (float)hx.x; e[k].y = (float)hx.y;
        }
      } else {
#pragma unroll
        for (int k = 0; k < NR; ++k) {
          const f4 t = *(const f4*)(Sp + swz(DB + t0 + 2 * k));
          if (2 * k     < B + 3) e[2 * k]     = lo2(t);
          if (2 * k + 1 < B + 3) e[2 * k + 1] = hi2(t);
        }
      }
    }
    f2 SE[B], SO[B];
#pragma unroll
    for (int j = 0; j < B; ++j) {
      SE[j] = a[j]*L1f + a[j+1]*L3f + a[j+2]*L5f + a[j+3]*L7f +
              e[j]*H1f + e[j+1]*H3f + e[j+2]*H5f + e[j+3]*H7f;
      SO[j] = a[j]*L0f + a[j+1]*L2f + a[j+2]*L4f + a[j+3]*L6f +
              e[j]*H0f + e[j+1]*H2f + e[j+2]*H4f + e[j+3]*H6f;
    }
    if constexpr (GOUT) {     // OUT=512, B=4: full; float4 global stores
      const int q0 = 2 * t0; // = 8*lane
      *reinterpret_cast<float4*>(gA + q0)     = make_float4(SE[0].x, SO[0].x, SE[1].x, SO[1].x);
      *reinterpret_cast<float4*>(gA + q0 + 4) = make_float4(SE[2].x, SO[2].x, SE[3].x, SO[3].x);
      if (hasB) {
        *reinterpret_cast<float4*>(gB + q0)     = make_float4(SE[0].y, SO[0].y, SE[1].y, SO[1].y);
        *reinterpret_cast<float4*>(gB + q0 + 4) = make_float4(SE[2].y, SO[2].y, SE[3].y, SO[3].y);
      }
    } else {
      const bool full = (t0 + B <= P) && (2 * (t0 + B) <= OUT);
      if (full) {
#pragma unroll
        for (int j = 0; j < B; ++j) {
          f4 r; r.x = SE[j].x; r.y = SE[j].y; r.z = SO[j].x; r.w = SO[j].y;
          *(f4*)(Sp + swz(DSTB + 2 * (t0 + j))) = r;
        }
      } else {
#pragma unroll
        for (int j = 0; j < B; ++j) {
          const int t = t0 + j;
          if (t < P) {
            const int q = 2 * t;
            Sp[swz(DSTB + q)] = SE[j];
            if (q + 1 < OUT) Sp[swz(DSTB + q + 1)] = SO[j];
          }
        }
      }
    }
  }
  if constexpr (64 * B < P) {   // tail pairs (inv3 only: t=128,129)
    const int tt = 64 * B + lane;
    if (tt < P) {
      f2 a0 = Sp[swz(CAB + tt)],     a1 = Sp[swz(CAB + tt + 1)];
      f2 a2 = Sp[swz(CAB + tt + 2)], a3 = Sp[swz(CAB + tt + 3)];
      f2 e0 = Sp[swz(DB + tt)],      e1 = Sp[swz(DB + tt + 1)];
      f2 e2 = Sp[swz(DB + tt + 2)],  e3 = Sp[swz(DB + tt + 3)];
      const f2 se = a0*L1f + a1*L3f + a2*L5f + a3*L7f +
                    e0*H1f + e1*H3f + e2*H5f + e3*H7f;
      const f2 so = a0*L0f + a1*L2f + a2*L4f + a3*L6f +
                    e0*H0f + e1*H2f + e2*H4f + e3*H6f;
      const int q = 2 * tt;
      Sp[swz(DSTB + q)] = se;
      if (q + 1 < OUT) Sp[swz(DSTB + q + 1)] = so;
    }
  }
}

// One wave per ROW PAIR; fwd1 streams directly from GLOBAL (no sx staging).
__global__ __launch_bounds__(128, 5) void wavelet_denoise_kernel(
    const float* __restrict__ x, float* __restrict__ out, int nrows) {
  __shared__ __align__(16) f2 lds[WPB][SLICE_F2];  // 14848 B/block
  const int wave = threadIdx.x >> 6;
  const int lane = threadIdx.x & 63;
  const int nPairs = (nrows + 1) >> 1;
  const int pairId = blockIdx.x * WPB + wave;
  if (pairId >= nPairs) return;  // no block barriers -> early exit safe

  const int rA = 2 * pairId;
  const bool hasB = (rA + 1) < nrows;
  const int rBc = hasB ? rA + 1 : rA;  // duplicate A into .y if no row B
  const float* __restrict__ xA = x + (size_t)rA * 512;
  const float* __restrict__ xB = x + (size_t)rBc * 512;

  f2* Sp = lds[wave];

  // ---- fwd1: N=512 -> M=259, B=4, straight from global ----
  // lane l (>=1): window x[8l-6..8l+7] per row, from 4 aligned float4 loads
  // covering [8l-8, 8l+8). Lane 0 mirrors ext[-6..-1]=x[5..0] from registers.
  {
    float aw[16], bw[16];
    if (lane == 0) {
      const float4 a0 = *(const float4*)(xA);      // x[0..3]
      const float4 a1 = *(const float4*)(xA + 4);  // x[4..7]
      const float4 b0 = *(const float4*)(xB);
      const float4 b1 = *(const float4*)(xB + 4);
      aw[8]=a0.x; aw[9]=a0.y; aw[10]=a0.z; aw[11]=a0.w;
      aw[12]=a1.x; aw[13]=a1.y; aw[14]=a1.z; aw[15]=a1.w;
      aw[7]=a0.x; aw[6]=a0.y; aw[5]=a0.z; aw[4]=a0.w;  // ext[-1..-4]=x[0..3]
      aw[3]=a1.x; aw[2]=a1.y; aw[1]=0.f; aw[0]=0.f;    // ext[-5,-6]=x[4,5]
      bw[8]=b0.x; bw[9]=b0.y; bw[10]=b0.z; bw[11]=b0.w;
      bw[12]=b1.x; bw[13]=b1.y; bw[14]=b1.z; bw[15]=b1.w;
      bw[7]=b0.x; bw[6]=b0.y; bw[5]=b0.z; bw[4]=b0.w;
      bw[3]=b1.x; bw[2]=b1.y; bw[1]=0.f; bw[0]=0.f;
    } else {
      const float* pA = xA + 8 * lane - 8;
      const float* pB = xB + 8 * lane - 8;
      const float4 a0 = *(const float4*)(pA);
      const float4 a1 = *(const float4*)(pA + 4);
      const float4 a2 = *(const float4*)(pA + 8);
      const float4 a3 = *(const float4*)(pA + 12);
      const float4 b0 = *(const float4*)(pB);
      const float4 b1 = *(const float4*)(pB + 4);
      const float4 b2 = *(const float4*)(pB + 8);
      const float4 b3 = *(const float4*)(pB + 12);
      aw[0]=a0.x; aw[1]=a0.y; aw[2]=a0.z; aw[3]=a0.w;
      aw[4]=a1.x; aw[5]=a1.y; aw[6]=a1.z; aw[7]=a1.w;
      aw[8]=a2.x; aw[9]=a2.y; aw[10]=a2.z; aw[11]=a2.w;
      aw[12]=a3.x; aw[13]=a3.y; aw[14]=a3.z; aw[15]=a3.w;
      bw[0]=b0.x; bw[1]=b0.y; bw[2]=b0.z; bw[3]=b0.w;
      bw[4]=b1.x; bw[5]=b1.y; bw[6]=b1.z; bw[7]=b1.w;
      bw[8]=b2.x; bw[9]=b2.y; bw[10]=b2.z; bw[11]=b2.w;
      bw[12]=b3.x; bw[13]=b3.y; bw[14]=b3.z; bw[15]=b3.w;
    }
    const int i0 = 4 * lane;   // 0..252; outputs i0..i0+3 all < 259
    f2 sA[4], sD[4];
#pragma unroll
    for (int j = 0; j < 4; ++j) {
      f2 v[8];
#pragma unroll
      for (int t = 0; t < 8; ++t) {
        f2 vv; vv.x = aw[2*j + t + 2]; vv.y = bw[2*j + t + 2];
        v[t] = vv;
      }
      f2 lo, hi;
      fwd_core(v[0], v[1], v[2], v[3], v[4], v[5], v[6], v[7], lo, hi);
      sA[j] = lo;
      f2 d; d.x = thr(hi.x); d.y = thr(hi.y);
      sD[j] = d;
      const int i = i0 + j;
      if (i < 6)    Sp[swz(CA1B - 1 - i)]   = lo;   // left mirror
      if (i >= 252) Sp[swz(CA1B + 517 - i)] = lo;   // right mirror (2M-1-i)
    }
    f4 c0; c0.x=sA[0].x; c0.y=sA[0].y; c0.z=sA[1].x; c0.w=sA[1].y;
    f4 c1; c1.x=sA[2].x; c1.y=sA[2].y; c1.z=sA[3].x; c1.w=sA[3].y;
    *(f4*)(Sp + swz(CA1B + i0))     = c0;
    *(f4*)(Sp + swz(CA1B + i0 + 2)) = c1;
    h8 hv;
    hv[0]=(_Float16)sD[0].x; hv[1]=(_Float16)sD[0].y;   // d1 f16: |d|<=10,
    hv[2]=(_Float16)sD[1].x; hv[3]=(_Float16)sD[1].y;   // err<0.01, never
    hv[4]=(_Float16)sD[2].x; hv[5]=(_Float16)sD[2].y;   // feeds a threshold
    hv[6]=(_Float16)sD[3].x; hv[7]=(_Float16)sD[3].y;
    *(h8*)(Sp + swz(D1B + 2 * lane)) = hv;
    // tail outputs i=256..258 (lanes 0..2): symmetric window from global
    if (lane < 3) {
      const int i = 256 + lane;
      f2 v[8];
#pragma unroll
      for (int t = 0; t < 8; ++t) {
        const int k = 2 * i - 6 + t;               // 506..517
        const int s = (k <= 511) ? k : 1023 - k;   // right mirror
        f2 vv; vv.x = xA[s]; vv.y = xB[s];
        v[t] = vv;
      }
      f2 lo, hi;
      fwd_core(v[0], v[1], v[2], v[3], v[4], v[5], v[6], v[7], lo, hi);
      Sp[swz(CA1B + i)] = lo;
      Sp[swz(CA1B + 517 - i)] = lo;                // right mirror (259..261)
      const float dx = thr(hi.x), dy = thr(hi.y);
      h2 r; r.x = (_Float16)dx; r.y = (_Float16)dy;
      ((h2*)(Sp + swz(D1B + (i >> 1))))[i & 1] = r;
    }
  }
  wave_sync();

  // analysis: 259 -> 133 -> 70 -> 38
  fwd_lds<259, 3, true >(Sp, CA1B, CA2B, D2B, lane); wave_sync();
  fwd_lds<133, 2, true >(Sp, CA2B, CA3B, D3B, lane); wave_sync();
  fwd_lds< 70, 1, false>(Sp, CA3B, CA4B, D4B, lane); wave_sync();

  // synthesis: 38 -> 70 -> 133 -> 259 -> 512
  float* gA = out + (size_t)rA * 512;
  float* gB = out + (size_t)rBc * 512;
  inv_lds< 70, 1, false, false>(Sp, CA4B,   D4B, REC70B,  nullptr, nullptr, false, lane);
  wave_sync();
  inv_lds<133, 2, false, false>(Sp, REC70B, D3B, REC133B, nullptr, nullptr, false, lane);
  wave_sync();
  inv_lds<259, 2, false, false>(Sp, REC133B, D2B, REC259B, nullptr, nullptr, false, lane);
  wave_sync();
  inv_lds<512, 4, true,  true >(Sp, REC259B, D1B, 0, gA, gB, hasB, lane);
}

extern "C" void kernel_launch(void* const* d_in, const int* in_sizes, int n_in,
                              void* d_out, int out_size, void* d_ws, size_t ws_size,
                              hipStream_t stream) {
  const float* x = (const float*)d_in[0];  // (nrows, 512) fp32
  float* out = (float*)d_out;              // (nrows, 512) fp32
  const int nrows = in_sizes[0] / 512;
  const int nPairs = (nrows + 1) >> 1;
  const int grid = (nPairs + WPB - 1) / WPB;
  wavelet_denoise_kernel<<<dim3(grid), dim3(WPB * 64), 0, stream>>>(x, out, nrows);
}